// Round 6
// baseline (973.941 us; speedup 1.0000x reference)
//
#include <hip/hip_runtime.h>
#include <hip/hip_bf16.h>

// Problem constants
#define B_N   4
#define CIN_  256
#define HH_   56
#define WW_   56
#define COUT_ 256
#define KK_   9
#define HW_   3136              // 56*56
#define KDIM  2304              // CIN_*KK_  (k index = kk*256 + ci)
#define NOFF  (B_N*18*HW_)      // 225792

typedef __attribute__((ext_vector_type(8))) short short8;   // 8 bf16 (4 VGPRs)
typedef __attribute__((ext_vector_type(4))) float float4v;  // MFMA accum

__device__ __forceinline__ short f2bf_bits(float v) {
    union { __hip_bfloat16 h; short s; } u;
    u.h = __float2bfloat16(v);
    return u.s;
}

// ---------------------------------------------------------------------------
// k_owt: transpose offset weights [18][256][9] -> owT[ci][c*9+kk] fp32
// ---------------------------------------------------------------------------
__global__ __launch_bounds__(256) void k_owt(const float* __restrict__ ow,
                                             float* __restrict__ owT) {
    int i = blockIdx.x*256 + threadIdx.x;        // i = ci*162 + c*9 + kk
    if (i >= 18*CIN_*KK_) return;
    int ci = i / 162; int r = i % 162;
    int c = r / 9;    int kk = r % 9;
    owT[i] = ow[(size_t)(c*CIN_ + ci)*9 + kk];
}

// ---------------------------------------------------------------------------
// k_prep: weight [Cout][Cin][9] fp32 -> At[cout][k=kk*256+ci] bf16
// ---------------------------------------------------------------------------
__global__ __launch_bounds__(256) void k_prep(const float* __restrict__ wgt,
                                              short* __restrict__ At) {
    int i = blockIdx.x*256 + threadIdx.x;        // i = o*2304 + kk*256 + ci
    if (i >= COUT_*KDIM) return;
    int o = i / KDIM; int r = i % KDIM;
    int kk = r >> 8;  int ci = r & 255;
    At[i] = f2bf_bits(wgt[(size_t)(o*CIN_ + ci)*9 + kk]);
}

// ---------------------------------------------------------------------------
// k_offset3: 3x3 offset conv, ci-split 8 ways for occupancy. DETERMINISTIC:
// each (block, ci-group) writes its partial to pOff[cg] (plain stores, no
// atomics) — atomic fp32 ordering jitter feeds floorf() downstream and
// flips bilinear corners nondeterministically across graph replays.
// Grid (224, 8): block = (b,h) x ci-group of 32. Wave q handles 8 ci.
// ---------------------------------------------------------------------------
__global__ __launch_bounds__(256) void k_offset3(const float* __restrict__ x,
                                                 const float* __restrict__ owT,
                                                 float* __restrict__ pOff) {
    __shared__ float red[4][18][64];             // 18 KB
    int t = threadIdx.x;
    int w = t & 63;  int q = t >> 6;
    int b = blockIdx.x / HH_, h = blockIdx.x % HH_;
    int cg = blockIdx.y;                         // 0..7
    const float* xb = x + (size_t)b*CIN_*HW_;

    float acc[18];
    #pragma unroll
    for (int c = 0; c < 18; ++c) acc[c] = 0.f;

    #pragma unroll
    for (int i = 0; i < 8; ++i) {
        int ci = cg*32 + q*8 + i;                // wave-uniform
        const float* xp = xb + (size_t)ci*HW_;
        float v[3], patch[9];
        #pragma unroll
        for (int kh = 0; kh < 3; ++kh) {
            int yy = h - 1 + kh;
            v[kh] = (w < WW_ && yy >= 0 && yy < HH_) ? xp[yy*WW_ + w] : 0.f;
        }
        #pragma unroll
        for (int kh = 0; kh < 3; ++kh) {
            float c0 = v[kh];
            float l = __shfl_up(c0, 1);  if (w == 0) l = 0.f;
            float r = __shfl_down(c0, 1);          // lanes >=56 hold 0 -> col-56 pad ok
            patch[kh*3+0] = l; patch[kh*3+1] = c0; patch[kh*3+2] = r;
        }
        const float* wp = owT + (size_t)ci*162;  // wave-uniform address
        #pragma unroll
        for (int c = 0; c < 18; ++c) {
            float a = acc[c];
            #pragma unroll
            for (int kk = 0; kk < 9; ++kk) a += patch[kk]*wp[c*9+kk];
            acc[c] = a;
        }
    }
    #pragma unroll
    for (int c = 0; c < 18; ++c) red[q][c][w] = acc[c];
    __syncthreads();
    float* pbase = pOff + (size_t)cg*NOFF;
    for (int o = t; o < 18*WW_; o += 256) {
        int c = o / WW_, w2 = o % WW_;
        float s = red[0][c][w2] + red[1][c][w2] + red[2][c][w2] + red[3][c][w2];
        pbase[(size_t)(b*18 + c)*HW_ + h*WW_ + w2] = s;
    }
}

// ---------------------------------------------------------------------------
// k_reduce: offs[i] = sum_{cg=0..7} pOff[cg][i] + bias  (fixed order ->
// bit-exact reproducible across replays).
// ---------------------------------------------------------------------------
__global__ __launch_bounds__(256) void k_reduce(const float* __restrict__ pOff,
                                                const float* __restrict__ ob,
                                                float* __restrict__ offs) {
    int i = blockIdx.x*256 + threadIdx.x;
    if (i >= NOFF) return;
    float s = ob[(i / HW_) % 18];
    #pragma unroll
    for (int cg = 0; cg < 8; ++cg) s += pOff[(size_t)cg*NOFF + i];
    offs[i] = s;
}

// ---------------------------------------------------------------------------
// k_sample: build S[n][k] bf16 (n = b*3136+pos, k = kk*256+ci).
// Block = (b, kk, 64-pos strip). First 64 threads compute bilinear params
// (corner idx + weights, zero weight for OOB) into LDS; then all threads
// gather-blend 8 ci per pass (8 passes), one 16B store each.
// ---------------------------------------------------------------------------
__global__ __launch_bounds__(256) void k_sample(const float* __restrict__ x,
                                                const float* __restrict__ offs,
                                                short* __restrict__ S) {
    __shared__ int4   sI[64];
    __shared__ float4 sW[64];
    int t = threadIdx.x;
    int b = blockIdx.z, kk = blockIdx.y;
    int pos0 = blockIdx.x * 64;

    if (t < 64) {
        int pos = pos0 + t;
        int h = pos / WW_, w = pos % WW_;
        float dy = offs[(size_t)(b*18 + 2*kk    )*HW_ + pos];
        float dx = offs[(size_t)(b*18 + 2*kk + 1)*HW_ + pos];
        float py = (float)(h - 1 + kk/3) + dy;
        float px = (float)(w - 1 + kk%3) + dx;
        float y0f = floorf(py), x0f = floorf(px);
        int y0 = (int)y0f, x0 = (int)x0f;
        float ty = py - y0f, tx = px - x0f;
        int   ys[2] = {y0, y0 + 1},   xs[2] = {x0, x0 + 1};
        float wy[2] = {1.f - ty, ty}, wx[2] = {1.f - tx, tx};
        int idx[4]; float wt[4];
        #pragma unroll
        for (int jy = 0; jy < 2; ++jy)
            #pragma unroll
            for (int jx = 0; jx < 2; ++jx) {
                int j = jy*2 + jx;
                int yy = ys[jy], xx = xs[jx];
                bool vd = (yy >= 0) && (yy < HH_) && (xx >= 0) && (xx < WW_);
                int yc = min(max(yy, 0), HH_-1);
                int xc = min(max(xx, 0), WW_-1);
                idx[j] = yc*WW_ + xc;
                wt[j]  = vd ? wy[jy]*wx[jx] : 0.f;
            }
        sI[t] = make_int4(idx[0], idx[1], idx[2], idx[3]);
        sW[t] = make_float4(wt[0], wt[1], wt[2], wt[3]);
    }
    __syncthreads();

    int lane = t & 63;  int g = t >> 6;
    int4   id = sI[lane];
    float4 wv = sW[lane];
    const float* xb = x + (size_t)b*CIN_*HW_;
    size_t nrow = (size_t)(b*HW_ + pos0 + lane)*KDIM + kk*256;

    for (int cc = 0; cc < 8; ++cc) {
        int ci0 = cc*32 + g*8;
        short8 pack;
        #pragma unroll
        for (int j = 0; j < 8; ++j) {
            const float* xr = xb + (size_t)(ci0 + j)*HW_;
            float v = wv.x*xr[id.x] + wv.y*xr[id.y]
                    + wv.z*xr[id.z] + wv.w*xr[id.w];
            pack[j] = f2bf_bits(v);
        }
        *(short8*)(S + nrow + ci0) = pack;       // 16B store
    }
}

// ---------------------------------------------------------------------------
// k_gemm: out[b][cout][pos] = sum_k At[cout][k] * S[n][k], bf16 MFMA
// 16x16x32, fp32 accum. BM=BN=64, BK=32, 256 threads = 4 waves (2x2).
// Grid (4, 196): x = m so the 4 m-blocks sharing one S-slice are
// dispatch-adjacent -> S re-reads hit L2/L3.
// ---------------------------------------------------------------------------
__global__ __launch_bounds__(256) void k_gemm(const short* __restrict__ At,
                                              const short* __restrict__ S,
                                              float* __restrict__ out) {
    __shared__ short sA[64][40];
    __shared__ short sB[64][40];
    int t = threadIdx.x;
    int m0 = blockIdx.x * 64;    // 4 m-blocks
    int n0 = blockIdx.y * 64;    // 196 n-blocks

    int row = t >> 2;            // staging row 0..63
    int kof = (t & 3) * 8;       // 0,8,16,24

    int wv = t >> 6;
    int wm = (wv >> 1) * 32;
    int wn = (wv & 1) * 32;
    int lane = t & 63;
    int lm = lane & 15;
    int qd = lane >> 4;

    float4v acc[2][2];
    #pragma unroll
    for (int i = 0; i < 2; ++i)
        #pragma unroll
        for (int j = 0; j < 2; ++j) acc[i][j] = (float4v)(0.f);

    const short* gA = At + (size_t)(m0 + row)*KDIM + kof;
    const short* gB = S  + (size_t)(n0 + row)*KDIM + kof;

    for (int kt = 0; kt < KDIM; kt += 32) {
        __syncthreads();
        *(short8*)&sA[row][kof] = *(const short8*)(gA + kt);
        *(short8*)&sB[row][kof] = *(const short8*)(gB + kt);
        __syncthreads();
        short8 af[2], bf[2];
        #pragma unroll
        for (int i = 0; i < 2; ++i) {
            af[i] = *(short8*)&sA[wm + i*16 + lm][qd*8];
            bf[i] = *(short8*)&sB[wn + i*16 + lm][qd*8];
        }
        #pragma unroll
        for (int i = 0; i < 2; ++i)
            #pragma unroll
            for (int j = 0; j < 2; ++j)
                acc[i][j] = __builtin_amdgcn_mfma_f32_16x16x32_bf16(
                                af[i], bf[j], acc[i][j], 0, 0, 0);
    }

    // epilogue: C/D layout col=lane&15 (n), row=qd*4+r (m)
    int b    = blockIdx.y / 49;
    int posb = (blockIdx.y % 49) * 64;
    #pragma unroll
    for (int i = 0; i < 2; ++i)
        #pragma unroll
        for (int j = 0; j < 2; ++j) {
            int col = posb + wn + j*16 + lm;
            #pragma unroll
            for (int r = 0; r < 4; ++r) {
                int m = m0 + wm + i*16 + qd*4 + r;
                out[((size_t)b*COUT_ + m)*HW_ + col] = acc[i][j][r];
            }
        }
}

// ---------------------------------------------------------------------------
extern "C" void kernel_launch(void* const* d_in, const int* in_sizes, int n_in,
                              void* d_out, int out_size, void* d_ws, size_t ws_size,
                              hipStream_t stream) {
    const float* x   = (const float*)d_in[0];
    const float* wgt = (const float*)d_in[1];
    const float* ow  = (const float*)d_in[2];
    const float* ob  = (const float*)d_in[3];
    float* out = (float*)d_out;

    char* ws = (char*)d_ws;
    // ws layout (16B aligned): offs | At | owT | S | pOff
    float* offs = (float*)ws;                        // 225792*4   =   903168
    short* At   = (short*)(ws + 903168);             // 589824*2   =  1179648
    float* owT  = (float*)(ws + 2082816);            // 41472*4    =   165888
    short* S    = (short*)(ws + 2248704);            // 28901376*2 = 57802752
    float* pOff = (float*)(ws + 60051456);           // 8*225792*4 =  7225344
                                                     // total ~67.3 MB

    k_owt    <<<dim3((18*CIN_*KK_ + 255)/256), 256, 0, stream>>>(ow, owT);
    k_prep   <<<dim3((COUT_*KDIM + 255)/256),  256, 0, stream>>>(wgt, At);
    k_offset3<<<dim3(B_N*HH_, 8),              256, 0, stream>>>(x, owT, pOff);
    k_reduce <<<dim3((NOFF + 255)/256),        256, 0, stream>>>(pOff, ob, offs);
    k_sample <<<dim3(49, 9, 4),                256, 0, stream>>>(x, offs, S);
    k_gemm   <<<dim3(4, 196),                  256, 0, stream>>>(At, S, out);
}

// Round 7
// 282.160 us; speedup vs baseline: 3.4517x; 3.4517x over previous
//
#include <hip/hip_runtime.h>
#include <hip/hip_bf16.h>

// Problem constants
#define B_N   4
#define CIN_  256
#define HH_   56
#define WW_   56
#define COUT_ 256
#define KK_   9
#define HW_   3136              // 56*56
#define KDIM  2304              // CIN_*KK_  (k index = kk*256 + ci)
#define NOFF  (B_N*18*HW_)      // 225792

typedef __attribute__((ext_vector_type(8))) short short8;   // 8 bf16 (4 VGPRs)
typedef __attribute__((ext_vector_type(4))) float float4v;  // MFMA accum

__device__ __forceinline__ short f2bf_bits(float v) {
    union { __hip_bfloat16 h; short s; } u;
    u.h = __float2bfloat16(v);
    return u.s;
}

// ---------------------------------------------------------------------------
// k_owt: transpose offset weights [18][256][9] -> owT[ci][c*9+kk] fp32
// ---------------------------------------------------------------------------
__global__ __launch_bounds__(256) void k_owt(const float* __restrict__ ow,
                                             float* __restrict__ owT) {
    int i = blockIdx.x*256 + threadIdx.x;        // i = ci*162 + c*9 + kk
    if (i >= 18*CIN_*KK_) return;
    int ci = i / 162; int r = i % 162;
    int c = r / 9;    int kk = r % 9;
    owT[i] = ow[(size_t)(c*CIN_ + ci)*9 + kk];
}

// ---------------------------------------------------------------------------
// k_prep: weight [Cout][Cin][9] fp32 -> At[cout][k=kk*256+ci] bf16
// ---------------------------------------------------------------------------
__global__ __launch_bounds__(256) void k_prep(const float* __restrict__ wgt,
                                              short* __restrict__ At) {
    int i = blockIdx.x*256 + threadIdx.x;        // i = o*2304 + kk*256 + ci
    if (i >= COUT_*KDIM) return;
    int o = i / KDIM; int r = i % KDIM;
    int kk = r >> 8;  int ci = r & 255;
    At[i] = f2bf_bits(wgt[(size_t)(o*CIN_ + ci)*9 + kk]);
}

// ---------------------------------------------------------------------------
// k_offset3: 3x3 offset conv, ci-split 8 ways for occupancy. DETERMINISTIC
// partials into pOff[cg] (no atomics: fp32 atomic jitter feeds floorf and
// flips bilinear corners across replays). Grid (224, 8); wave q handles 8 ci.
// NOTE: ci loop MUST NOT unroll — unrolling it ballooned VGPRs to 256 and
// spilled 1.9 GB/dispatch to scratch (round-6 counters).
// ---------------------------------------------------------------------------
__global__ __launch_bounds__(256) void k_offset3(const float* __restrict__ x,
                                                 const float* __restrict__ owT,
                                                 float* __restrict__ pOff) {
    __shared__ float red[4][18][64];             // 18 KB
    int t = threadIdx.x;
    int w = t & 63;  int q = t >> 6;
    int b = blockIdx.x / HH_, h = blockIdx.x % HH_;
    int cg = blockIdx.y;                         // 0..7
    const float* xb = x + (size_t)b*CIN_*HW_;

    float acc[18];
    #pragma unroll
    for (int c = 0; c < 18; ++c) acc[c] = 0.f;

    #pragma unroll 1
    for (int i = 0; i < 8; ++i) {
        int ci = cg*32 + q*8 + i;                // wave-uniform
        const float* xp = xb + (size_t)ci*HW_;
        float v[3], patch[9];
        #pragma unroll
        for (int kh = 0; kh < 3; ++kh) {
            int yy = h - 1 + kh;
            v[kh] = (w < WW_ && yy >= 0 && yy < HH_) ? xp[yy*WW_ + w] : 0.f;
        }
        #pragma unroll
        for (int kh = 0; kh < 3; ++kh) {
            float c0 = v[kh];
            float l = __shfl_up(c0, 1);  if (w == 0) l = 0.f;
            float r = __shfl_down(c0, 1);          // lanes >=56 hold 0 -> col-56 pad ok
            patch[kh*3+0] = l; patch[kh*3+1] = c0; patch[kh*3+2] = r;
        }
        const float* wp = owT + (size_t)ci*162;  // wave-uniform address
        #pragma unroll
        for (int c = 0; c < 18; ++c) {
            float a = acc[c];
            #pragma unroll
            for (int kk = 0; kk < 9; ++kk) a += patch[kk]*wp[c*9+kk];
            acc[c] = a;
        }
    }
    #pragma unroll
    for (int c = 0; c < 18; ++c) red[q][c][w] = acc[c];
    __syncthreads();
    float* pbase = pOff + (size_t)cg*NOFF;
    for (int o = t; o < 18*WW_; o += 256) {
        int c = o / WW_, w2 = o % WW_;
        float s = red[0][c][w2] + red[1][c][w2] + red[2][c][w2] + red[3][c][w2];
        pbase[(size_t)(b*18 + c)*HW_ + h*WW_ + w2] = s;
    }
}

// ---------------------------------------------------------------------------
// k_reduce: offs[i] = sum_{cg} pOff[cg][i] + bias  (fixed order, bit-exact
// across replays).
// ---------------------------------------------------------------------------
__global__ __launch_bounds__(256) void k_reduce(const float* __restrict__ pOff,
                                                const float* __restrict__ ob,
                                                float* __restrict__ offs) {
    int i = blockIdx.x*256 + threadIdx.x;
    if (i >= NOFF) return;
    float s = ob[(i / HW_) % 18];
    #pragma unroll
    for (int cg = 0; cg < 8; ++cg) s += pOff[(size_t)cg*NOFF + i];
    offs[i] = s;
}

// ---------------------------------------------------------------------------
// k_sample: build S[n][k] bf16 (n = b*3136+pos, k = kk*256+ci).
// Block = (b, kk, 64-pos strip). First 64 threads compute bilinear params
// (corner idx + weights, zero weight for OOB) into LDS; then all threads
// gather-blend 8 ci per pass (8 passes), one 16B store each.
// ---------------------------------------------------------------------------
__global__ __launch_bounds__(256) void k_sample(const float* __restrict__ x,
                                                const float* __restrict__ offs,
                                                short* __restrict__ S) {
    __shared__ int4   sI[64];
    __shared__ float4 sW[64];
    int t = threadIdx.x;
    int b = blockIdx.z, kk = blockIdx.y;
    int pos0 = blockIdx.x * 64;

    if (t < 64) {
        int pos = pos0 + t;
        int h = pos / WW_, w = pos % WW_;
        float dy = offs[(size_t)(b*18 + 2*kk    )*HW_ + pos];
        float dx = offs[(size_t)(b*18 + 2*kk + 1)*HW_ + pos];
        float py = (float)(h - 1 + kk/3) + dy;
        float px = (float)(w - 1 + kk%3) + dx;
        float y0f = floorf(py), x0f = floorf(px);
        int y0 = (int)y0f, x0 = (int)x0f;
        float ty = py - y0f, tx = px - x0f;
        int   ys[2] = {y0, y0 + 1},   xs[2] = {x0, x0 + 1};
        float wy[2] = {1.f - ty, ty}, wx[2] = {1.f - tx, tx};
        int idx[4]; float wt[4];
        #pragma unroll
        for (int jy = 0; jy < 2; ++jy)
            #pragma unroll
            for (int jx = 0; jx < 2; ++jx) {
                int j = jy*2 + jx;
                int yy = ys[jy], xx = xs[jx];
                bool vd = (yy >= 0) && (yy < HH_) && (xx < WW_) && (xx >= 0);
                int yc = min(max(yy, 0), HH_-1);
                int xc = min(max(xx, 0), WW_-1);
                idx[j] = yc*WW_ + xc;
                wt[j]  = vd ? wy[jy]*wx[jx] : 0.f;
            }
        sI[t] = make_int4(idx[0], idx[1], idx[2], idx[3]);
        sW[t] = make_float4(wt[0], wt[1], wt[2], wt[3]);
    }
    __syncthreads();

    int lane = t & 63;  int g = t >> 6;
    int4   id = sI[lane];
    float4 wv = sW[lane];
    const float* xb = x + (size_t)b*CIN_*HW_;
    size_t nrow = (size_t)(b*HW_ + pos0 + lane)*KDIM + kk*256;

    for (int cc = 0; cc < 8; ++cc) {
        int ci0 = cc*32 + g*8;
        short8 pack;
        #pragma unroll
        for (int j = 0; j < 8; ++j) {
            const float* xr = xb + (size_t)(ci0 + j)*HW_;
            float v = wv.x*xr[id.x] + wv.y*xr[id.y]
                    + wv.z*xr[id.z] + wv.w*xr[id.w];
            pack[j] = f2bf_bits(v);
        }
        *(short8*)(S + nrow + ci0) = pack;       // 16B store
    }
}

// ---------------------------------------------------------------------------
// k_gemm: out[b][cout][pos] = sum_k At[cout][k] * S[n][k], bf16 MFMA
// 16x16x32, fp32 accum. BM=BN=64, BK=32, 256 threads = 4 waves (2x2).
// Grid (4, 196): x = m so the 4 m-blocks sharing one S-slice are
// dispatch-adjacent -> S re-reads hit L2/L3.
// ---------------------------------------------------------------------------
__global__ __launch_bounds__(256) void k_gemm(const short* __restrict__ At,
                                              const short* __restrict__ S,
                                              float* __restrict__ out) {
    __shared__ short sA[64][40];
    __shared__ short sB[64][40];
    int t = threadIdx.x;
    int m0 = blockIdx.x * 64;    // 4 m-blocks
    int n0 = blockIdx.y * 64;    // 196 n-blocks

    int row = t >> 2;            // staging row 0..63
    int kof = (t & 3) * 8;       // 0,8,16,24

    int wv = t >> 6;
    int wm = (wv >> 1) * 32;
    int wn = (wv & 1) * 32;
    int lane = t & 63;
    int lm = lane & 15;
    int qd = lane >> 4;

    float4v acc[2][2];
    #pragma unroll
    for (int i = 0; i < 2; ++i)
        #pragma unroll
        for (int j = 0; j < 2; ++j) acc[i][j] = (float4v)(0.f);

    const short* gA = At + (size_t)(m0 + row)*KDIM + kof;
    const short* gB = S  + (size_t)(n0 + row)*KDIM + kof;

    for (int kt = 0; kt < KDIM; kt += 32) {
        __syncthreads();
        *(short8*)&sA[row][kof] = *(const short8*)(gA + kt);
        *(short8*)&sB[row][kof] = *(const short8*)(gB + kt);
        __syncthreads();
        short8 af[2], bf[2];
        #pragma unroll
        for (int i = 0; i < 2; ++i) {
            af[i] = *(short8*)&sA[wm + i*16 + lm][qd*8];
            bf[i] = *(short8*)&sB[wn + i*16 + lm][qd*8];
        }
        #pragma unroll
        for (int i = 0; i < 2; ++i)
            #pragma unroll
            for (int j = 0; j < 2; ++j)
                acc[i][j] = __builtin_amdgcn_mfma_f32_16x16x32_bf16(
                                af[i], bf[j], acc[i][j], 0, 0, 0);
    }

    // epilogue: C/D layout col=lane&15 (n), row=qd*4+r (m)
    int b    = blockIdx.y / 49;
    int posb = (blockIdx.y % 49) * 64;
    #pragma unroll
    for (int i = 0; i < 2; ++i)
        #pragma unroll
        for (int j = 0; j < 2; ++j) {
            int col = posb + wn + j*16 + lm;
            #pragma unroll
            for (int r = 0; r < 4; ++r) {
                int m = m0 + wm + i*16 + qd*4 + r;
                out[((size_t)b*COUT_ + m)*HW_ + col] = acc[i][j][r];
            }
        }
}

// ---------------------------------------------------------------------------
extern "C" void kernel_launch(void* const* d_in, const int* in_sizes, int n_in,
                              void* d_out, int out_size, void* d_ws, size_t ws_size,
                              hipStream_t stream) {
    const float* x   = (const float*)d_in[0];
    const float* wgt = (const float*)d_in[1];
    const float* ow  = (const float*)d_in[2];
    const float* ob  = (const float*)d_in[3];
    float* out = (float*)d_out;

    char* ws = (char*)d_ws;
    // ws layout (16B aligned): offs | At | owT | S | pOff
    float* offs = (float*)ws;                        // 225792*4   =   903168
    short* At   = (short*)(ws + 903168);             // 589824*2   =  1179648
    float* owT  = (float*)(ws + 2082816);            // 41472*4    =   165888
    short* S    = (short*)(ws + 2248704);            // 28901376*2 = 57802752
    float* pOff = (float*)(ws + 60051456);           // 8*225792*4 =  7225344
                                                     // total ~67.3 MB

    k_owt    <<<dim3((18*CIN_*KK_ + 255)/256), 256, 0, stream>>>(ow, owT);
    k_prep   <<<dim3((COUT_*KDIM + 255)/256),  256, 0, stream>>>(wgt, At);
    k_offset3<<<dim3(B_N*HH_, 8),              256, 0, stream>>>(x, owT, pOff);
    k_reduce <<<dim3((NOFF + 255)/256),        256, 0, stream>>>(pOff, ob, offs);
    k_sample <<<dim3(49, 9, 4),                256, 0, stream>>>(x, offs, S);
    k_gemm   <<<dim3(4, 196),                  256, 0, stream>>>(At, S, out);
}

// Round 8
// 206.120 us; speedup vs baseline: 4.7251x; 1.3689x over previous
//
#include <hip/hip_runtime.h>
#include <hip/hip_bf16.h>

// Problem constants
#define B_N   4
#define CIN_  256
#define HH_   56
#define WW_   56
#define COUT_ 256
#define KK_   9
#define HW_   3136              // 56*56
#define KDIM  2304              // CIN_*KK_  (k index = kk*256 + ci)
#define NOFF  (B_N*18*HW_)      // 225792

typedef __attribute__((ext_vector_type(8))) short short8;   // 8 bf16 (4 VGPRs)
typedef __attribute__((ext_vector_type(4))) float float4v;  // MFMA accum

__device__ __forceinline__ short f2bf_bits(float v) {
    union { __hip_bfloat16 h; short s; } u;
    u.h = __float2bfloat16(v);
    return u.s;
}

// ---------------------------------------------------------------------------
// k_owt: offset weights [18][256][9] -> owT2[ci][c*12+kk] fp32 (stride 12 so
// each c-row is 16B-aligned for LDS float4 reads; kk=9..11 zero-filled).
// ---------------------------------------------------------------------------
__global__ __launch_bounds__(256) void k_owt(const float* __restrict__ ow,
                                             float* __restrict__ owT2) {
    int i = blockIdx.x*256 + threadIdx.x;        // i = ci*216 + c*12 + kk
    if (i >= CIN_*216) return;
    int ci = i / 216; int r = i % 216;
    int c = r / 12;   int kk = r % 12;
    owT2[i] = (kk < 9) ? ow[(size_t)(c*CIN_ + ci)*9 + kk] : 0.f;
}

// ---------------------------------------------------------------------------
// k_prep: weight [Cout][Cin][9] fp32 -> At[cout][k=kk*256+ci] bf16
// ---------------------------------------------------------------------------
__global__ __launch_bounds__(256) void k_prep(const float* __restrict__ wgt,
                                              short* __restrict__ At) {
    int i = blockIdx.x*256 + threadIdx.x;        // i = o*2304 + kk*256 + ci
    if (i >= COUT_*KDIM) return;
    int o = i / KDIM; int r = i % KDIM;
    int kk = r >> 8;  int ci = r & 255;
    At[i] = f2bf_bits(wgt[(size_t)(o*CIN_ + ci)*9 + kk]);
}

// ---------------------------------------------------------------------------
// k_offset3: 3x3 offset conv, ci-split 8 ways. DETERMINISTIC partials into
// pOff[cg] (no atomics — fp32 atomic jitter feeds floorf downstream and
// flips bilinear corners across replays). Weights staged in LDS, read as
// wave-uniform broadcasts (r7 showed 85us with VALUBusy 23%: the 162 global
// weight loads per ci were a latency chain). red[] aliases the weight LDS.
// ci loop MUST NOT unroll (r6: unroll -> 256 VGPR -> 1.9GB scratch spill).
// ---------------------------------------------------------------------------
__global__ __launch_bounds__(256) void k_offset3(const float* __restrict__ x,
                                                 const float* __restrict__ owT2,
                                                 float* __restrict__ pOff) {
    __shared__ float smem[32*216];               // 27.6 KB: weights, then red
    int t = threadIdx.x;
    int w = t & 63;  int q = t >> 6;
    int b = blockIdx.x / HH_, h = blockIdx.x % HH_;
    int cg = blockIdx.y;                         // 0..7
    const float* xb = x + (size_t)b*CIN_*HW_;

    // stage this block's 32-ci weight slice (coalesced, layout-identical)
    {
        const float* src = owT2 + (size_t)cg*32*216;
        for (int i = t; i < 32*216; i += 256) smem[i] = src[i];
    }
    __syncthreads();

    float acc[18];
    #pragma unroll
    for (int c = 0; c < 18; ++c) acc[c] = 0.f;

    #pragma unroll 1
    for (int i = 0; i < 8; ++i) {
        int cil = q*8 + i;                       // ci local 0..31, wave-uniform
        const float* xp = xb + (size_t)(cg*32 + cil)*HW_;
        float v[3], patch[9];
        #pragma unroll
        for (int kh = 0; kh < 3; ++kh) {
            int yy = h - 1 + kh;
            v[kh] = (w < WW_ && yy >= 0 && yy < HH_) ? xp[yy*WW_ + w] : 0.f;
        }
        #pragma unroll
        for (int kh = 0; kh < 3; ++kh) {
            float c0 = v[kh];
            float l = __shfl_up(c0, 1);  if (w == 0) l = 0.f;
            float r = __shfl_down(c0, 1);        // lanes >=56 hold 0 -> col-56 pad ok
            patch[kh*3+0] = l; patch[kh*3+1] = c0; patch[kh*3+2] = r;
        }
        const float* wr_ = smem + cil*216;       // wave-uniform -> LDS broadcast
        #pragma unroll
        for (int c = 0; c < 18; ++c) {
            float4 wA = *(const float4*)(wr_ + c*12);      // 16B-aligned
            float4 wB = *(const float4*)(wr_ + c*12 + 4);
            float  w8 = wr_[c*12 + 8];
            acc[c] += patch[0]*wA.x + patch[1]*wA.y + patch[2]*wA.z + patch[3]*wA.w
                    + patch[4]*wB.x + patch[5]*wB.y + patch[6]*wB.z + patch[7]*wB.w
                    + patch[8]*w8;
        }
    }
    __syncthreads();                             // weights no longer needed
    float* red = smem;                           // red[q][c][w] = q*1152+c*64+w
    #pragma unroll
    for (int c = 0; c < 18; ++c) red[q*1152 + c*64 + w] = acc[c];
    __syncthreads();
    float* pbase = pOff + (size_t)cg*NOFF;
    for (int o = t; o < 18*WW_; o += 256) {
        int c = o / WW_, w2 = o % WW_;
        float s = red[0*1152 + c*64 + w2] + red[1*1152 + c*64 + w2]
                + red[2*1152 + c*64 + w2] + red[3*1152 + c*64 + w2];
        pbase[(size_t)(b*18 + c)*HW_ + h*WW_ + w2] = s;
    }
}

// ---------------------------------------------------------------------------
// k_reduce: offs[i] = sum_{cg} pOff[cg][i] + bias (fixed order, bit-exact).
// ---------------------------------------------------------------------------
__global__ __launch_bounds__(256) void k_reduce(const float* __restrict__ pOff,
                                                const float* __restrict__ ob,
                                                float* __restrict__ offs) {
    int i = blockIdx.x*256 + threadIdx.x;
    if (i >= NOFF) return;
    float s = ob[(i / HW_) % 18];
    #pragma unroll
    for (int cg = 0; cg < 8; ++cg) s += pOff[(size_t)cg*NOFF + i];
    offs[i] = s;
}

// ---------------------------------------------------------------------------
// k_sample: build S[n][k] bf16 (n = b*3136+pos, k = kk*256+ci).
// v2: paired-corner gathers. The two x-corners per bilinear row are adjacent
// addresses -> one float2 load per row (global dwordx2 needs only 4B align),
// halving gather instruction count (r7: 84us, VALUBusy 9%, HBM 20% ->
// gather-issue-bound). Per pos: bases b0,b1 (x clamped to <=W-2) + 4 folded
// coeffs (validity-masked + selector-folded; matches reference clip+mask).
// ---------------------------------------------------------------------------
__global__ __launch_bounds__(256) void k_sample(const float* __restrict__ x,
                                                const float* __restrict__ offs,
                                                short* __restrict__ S) {
    __shared__ int2   sI[64];
    __shared__ float4 sW[64];
    int t = threadIdx.x;
    int b = blockIdx.z, kk = blockIdx.y;
    int pos0 = blockIdx.x * 64;

    if (t < 64) {
        int pos = pos0 + t;
        int h = pos / WW_, w = pos % WW_;
        float dy = offs[(size_t)(b*18 + 2*kk    )*HW_ + pos];
        float dx = offs[(size_t)(b*18 + 2*kk + 1)*HW_ + pos];
        float py = (float)(h - 1 + kk/3) + dy;
        float px = (float)(w - 1 + kk%3) + dx;
        float y0f = floorf(py), x0f = floorf(px);
        int y0 = (int)y0f, x0 = (int)x0f;
        float ty = py - y0f, tx = px - x0f;
        bool vy0 = (y0 >= 0) && (y0 < HH_);
        bool vy1 = (y0+1 >= 0) && (y0+1 < HH_);
        bool vxl = (x0 >= 0) && (x0 < WW_);
        bool vxr = (x0+1 >= 0) && (x0+1 < WW_);
        int y0c = min(max(y0,     0), HH_-1);
        int y1c = min(max(y0 + 1, 0), HH_-1);
        int xc2 = min(max(x0, 0), WW_-2);        // float2 stays in-row
        int il  = min(max(x0     - xc2, 0), 1);  // left  corner -> v.x or v.y
        int ir  = min(max(x0 + 1 - xc2, 0), 1);  // right corner -> v.x or v.y
        float wxl = vxl ? (1.f - tx) : 0.f;
        float wxr = vxr ? tx : 0.f;
        float cx0 = (il == 0 ? wxl : 0.f) + (ir == 0 ? wxr : 0.f);
        float cx1 = (il == 1 ? wxl : 0.f) + (ir == 1 ? wxr : 0.f);
        float c00 = vy0 ? (1.f - ty)*cx0 : 0.f;
        float c01 = vy0 ? (1.f - ty)*cx1 : 0.f;
        float c10 = vy1 ? ty*cx0 : 0.f;
        float c11 = vy1 ? ty*cx1 : 0.f;
        sI[t] = make_int2(y0c*WW_ + xc2, y1c*WW_ + xc2);
        sW[t] = make_float4(c00, c01, c10, c11);
    }
    __syncthreads();

    int lane = t & 63;  int g = t >> 6;
    int2   id = sI[lane];
    float4 cw = sW[lane];
    const float* xb = x + (size_t)b*CIN_*HW_;
    size_t nrow = (size_t)(b*HW_ + pos0 + lane)*KDIM + kk*256;

    for (int cc = 0; cc < 8; ++cc) {
        int ci0 = cc*32 + g*8;
        short8 pack;
        #pragma unroll
        for (int j = 0; j < 8; ++j) {
            const float* xr = xb + (size_t)(ci0 + j)*HW_;
            float2 v0 = *(const float2*)(xr + id.x);
            float2 v1 = *(const float2*)(xr + id.y);
            float v = cw.x*v0.x + cw.y*v0.y + cw.z*v1.x + cw.w*v1.y;
            pack[j] = f2bf_bits(v);
        }
        *(short8*)(S + nrow + ci0) = pack;       // 16B store
    }
}

// ---------------------------------------------------------------------------
// k_gemm: out[b][cout][pos] = sum_k At[cout][k] * S[n][k], bf16 MFMA
// 16x16x32, fp32 accum. BM=BN=64, BK=32, 256 threads = 4 waves (2x2).
// Grid (4, 196): x = m so the 4 m-blocks sharing one S-slice are
// dispatch-adjacent -> S re-reads hit L2/L3.
// ---------------------------------------------------------------------------
__global__ __launch_bounds__(256) void k_gemm(const short* __restrict__ At,
                                              const short* __restrict__ S,
                                              float* __restrict__ out) {
    __shared__ short sA[64][40];
    __shared__ short sB[64][40];
    int t = threadIdx.x;
    int m0 = blockIdx.x * 64;    // 4 m-blocks
    int n0 = blockIdx.y * 64;    // 196 n-blocks

    int row = t >> 2;            // staging row 0..63
    int kof = (t & 3) * 8;       // 0,8,16,24

    int wv = t >> 6;
    int wm = (wv >> 1) * 32;
    int wn = (wv & 1) * 32;
    int lane = t & 63;
    int lm = lane & 15;
    int qd = lane >> 4;

    float4v acc[2][2];
    #pragma unroll
    for (int i = 0; i < 2; ++i)
        #pragma unroll
        for (int j = 0; j < 2; ++j) acc[i][j] = (float4v)(0.f);

    const short* gA = At + (size_t)(m0 + row)*KDIM + kof;
    const short* gB = S  + (size_t)(n0 + row)*KDIM + kof;

    for (int kt = 0; kt < KDIM; kt += 32) {
        __syncthreads();
        *(short8*)&sA[row][kof] = *(const short8*)(gA + kt);
        *(short8*)&sB[row][kof] = *(const short8*)(gB + kt);
        __syncthreads();
        short8 af[2], bf[2];
        #pragma unroll
        for (int i = 0; i < 2; ++i) {
            af[i] = *(short8*)&sA[wm + i*16 + lm][qd*8];
            bf[i] = *(short8*)&sB[wn + i*16 + lm][qd*8];
        }
        #pragma unroll
        for (int i = 0; i < 2; ++i)
            #pragma unroll
            for (int j = 0; j < 2; ++j)
                acc[i][j] = __builtin_amdgcn_mfma_f32_16x16x32_bf16(
                                af[i], bf[j], acc[i][j], 0, 0, 0);
    }

    // epilogue: C/D layout col=lane&15 (n), row=qd*4+r (m)
    int b    = blockIdx.y / 49;
    int posb = (blockIdx.y % 49) * 64;
    #pragma unroll
    for (int i = 0; i < 2; ++i)
        #pragma unroll
        for (int j = 0; j < 2; ++j) {
            int col = posb + wn + j*16 + lm;
            #pragma unroll
            for (int r = 0; r < 4; ++r) {
                int m = m0 + wm + i*16 + qd*4 + r;
                out[((size_t)b*COUT_ + m)*HW_ + col] = acc[i][j][r];
            }
        }
}

// ---------------------------------------------------------------------------
extern "C" void kernel_launch(void* const* d_in, const int* in_sizes, int n_in,
                              void* d_out, int out_size, void* d_ws, size_t ws_size,
                              hipStream_t stream) {
    const float* x   = (const float*)d_in[0];
    const float* wgt = (const float*)d_in[1];
    const float* ow  = (const float*)d_in[2];
    const float* ob  = (const float*)d_in[3];
    float* out = (float*)d_out;

    char* ws = (char*)d_ws;
    // ws layout (16B aligned): offs | At | owT2 | S | pOff
    float* offs = (float*)ws;                        // 225792*4   =   903168
    short* At   = (short*)(ws + 903168);             // 589824*2   =  1179648
    float* owT2 = (float*)(ws + 2082816);            // 55296*4    =   221184
    short* S    = (short*)(ws + 2304000);            // 28901376*2 = 57802752
    float* pOff = (float*)(ws + 60106752);           // 8*225792*4 =  7225344
                                                     // total ~67.3 MB

    k_owt    <<<dim3((CIN_*216 + 255)/256),   256, 0, stream>>>(ow, owT2);
    k_prep   <<<dim3((COUT_*KDIM + 255)/256), 256, 0, stream>>>(wgt, At);
    k_offset3<<<dim3(B_N*HH_, 8),             256, 0, stream>>>(x, owT2, pOff);
    k_reduce <<<dim3((NOFF + 255)/256),       256, 0, stream>>>(pOff, ob, offs);
    k_sample <<<dim3(49, 9, 4),               256, 0, stream>>>(x, offs, S);
    k_gemm   <<<dim3(4, 196),                 256, 0, stream>>>(At, S, out);
}

// Round 9
// 173.957 us; speedup vs baseline: 5.5987x; 1.1849x over previous
//
#include <hip/hip_runtime.h>
#include <hip/hip_bf16.h>

// Problem constants
#define B_N   4
#define CIN_  256
#define HH_   56
#define WW_   56
#define COUT_ 256
#define KK_   9
#define HW_   3136              // 56*56
#define KDIM  2304              // CIN_*KK_  (k index = kk*256 + ci)
#define NOFF  (B_N*18*HW_)      // 225792

typedef __attribute__((ext_vector_type(8))) short short8;   // 8 bf16 (4 VGPRs)
typedef __attribute__((ext_vector_type(4))) short short4v;  // 4 bf16 (8 B)
typedef __attribute__((ext_vector_type(4))) float float4v;  // MFMA accum

__device__ __forceinline__ short f2bf_bits(float v) {
    union { __hip_bfloat16 h; short s; } u;
    u.h = __float2bfloat16(v);
    return u.s;
}
__device__ __forceinline__ float bfbits2f(short s) {
    union { unsigned u; float f; } u2;
    u2.u = ((unsigned)(unsigned short)s) << 16;
    return u2.f;
}

// ---------------------------------------------------------------------------
// k_owt: offset weights [18][256][9] -> owT2[ci][c*12+kk] fp32 (stride 12 so
// each c-row is 16B-aligned for LDS float4 reads; kk=9..11 zero-filled).
// ---------------------------------------------------------------------------
__global__ __launch_bounds__(256) void k_owt(const float* __restrict__ ow,
                                             float* __restrict__ owT2) {
    int i = blockIdx.x*256 + threadIdx.x;        // i = ci*216 + c*12 + kk
    if (i >= CIN_*216) return;
    int ci = i / 216; int r = i % 216;
    int c = r / 12;   int kk = r % 12;
    owT2[i] = (kk < 9) ? ow[(size_t)(c*CIN_ + ci)*9 + kk] : 0.f;
}

// ---------------------------------------------------------------------------
// k_prep: weight [Cout][Cin][9] fp32 -> At[cout][k=kk*256+ci] bf16
// ---------------------------------------------------------------------------
__global__ __launch_bounds__(256) void k_prep(const float* __restrict__ wgt,
                                              short* __restrict__ At) {
    int i = blockIdx.x*256 + threadIdx.x;        // i = o*2304 + kk*256 + ci
    if (i >= COUT_*KDIM) return;
    int o = i / KDIM; int r = i % KDIM;
    int kk = r >> 8;  int ci = r & 255;
    At[i] = f2bf_bits(wgt[(size_t)(o*CIN_ + ci)*9 + kk]);
}

// ---------------------------------------------------------------------------
// k_offset3: 3x3 offset conv, ci-split 8 ways. DETERMINISTIC partials into
// pOff[cg] (no atomics — fp32 atomic jitter feeds floorf downstream and
// flips bilinear corners across replays). Weights staged in LDS, wave-uniform
// broadcast reads. red[] aliases weight LDS. ci loop MUST NOT unroll
// (r6: unroll -> 256 VGPR -> 1.9GB scratch spill).
// ---------------------------------------------------------------------------
__global__ __launch_bounds__(256) void k_offset3(const float* __restrict__ x,
                                                 const float* __restrict__ owT2,
                                                 float* __restrict__ pOff) {
    __shared__ float smem[32*216];               // 27.6 KB: weights, then red
    int t = threadIdx.x;
    int w = t & 63;  int q = t >> 6;
    int b = blockIdx.x / HH_, h = blockIdx.x % HH_;
    int cg = blockIdx.y;                         // 0..7
    const float* xb = x + (size_t)b*CIN_*HW_;

    {
        const float* src = owT2 + (size_t)cg*32*216;
        for (int i = t; i < 32*216; i += 256) smem[i] = src[i];
    }
    __syncthreads();

    float acc[18];
    #pragma unroll
    for (int c = 0; c < 18; ++c) acc[c] = 0.f;

    #pragma unroll 1
    for (int i = 0; i < 8; ++i) {
        int cil = q*8 + i;                       // ci local 0..31, wave-uniform
        const float* xp = xb + (size_t)(cg*32 + cil)*HW_;
        float v[3], patch[9];
        #pragma unroll
        for (int kh = 0; kh < 3; ++kh) {
            int yy = h - 1 + kh;
            v[kh] = (w < WW_ && yy >= 0 && yy < HH_) ? xp[yy*WW_ + w] : 0.f;
        }
        #pragma unroll
        for (int kh = 0; kh < 3; ++kh) {
            float c0 = v[kh];
            float l = __shfl_up(c0, 1);  if (w == 0) l = 0.f;
            float r = __shfl_down(c0, 1);        // lanes >=56 hold 0 -> col-56 pad ok
            patch[kh*3+0] = l; patch[kh*3+1] = c0; patch[kh*3+2] = r;
        }
        const float* wr_ = smem + cil*216;       // wave-uniform -> LDS broadcast
        #pragma unroll
        for (int c = 0; c < 18; ++c) {
            float4 wA = *(const float4*)(wr_ + c*12);
            float4 wB = *(const float4*)(wr_ + c*12 + 4);
            float  w8 = wr_[c*12 + 8];
            acc[c] += patch[0]*wA.x + patch[1]*wA.y + patch[2]*wA.z + patch[3]*wA.w
                    + patch[4]*wB.x + patch[5]*wB.y + patch[6]*wB.z + patch[7]*wB.w
                    + patch[8]*w8;
        }
    }
    __syncthreads();
    float* red = smem;                           // red[q][c][w] = q*1152+c*64+w
    #pragma unroll
    for (int c = 0; c < 18; ++c) red[q*1152 + c*64 + w] = acc[c];
    __syncthreads();
    float* pbase = pOff + (size_t)cg*NOFF;
    for (int o = t; o < 18*WW_; o += 256) {
        int c = o / WW_, w2 = o % WW_;
        float s = red[0*1152 + c*64 + w2] + red[1*1152 + c*64 + w2]
                + red[2*1152 + c*64 + w2] + red[3*1152 + c*64 + w2];
        pbase[(size_t)(b*18 + c)*HW_ + h*WW_ + w2] = s;
    }
}

// ---------------------------------------------------------------------------
// k_reduce: offs[i] = sum_{cg} pOff[cg][i] + bias (fixed order, bit-exact).
// ---------------------------------------------------------------------------
__global__ __launch_bounds__(256) void k_reduce(const float* __restrict__ pOff,
                                                const float* __restrict__ ob,
                                                float* __restrict__ offs) {
    int i = blockIdx.x*256 + threadIdx.x;
    if (i >= NOFF) return;
    float s = ob[(i / HW_) % 18];
    #pragma unroll
    for (int cg = 0; cg < 8; ++cg) s += pOff[(size_t)cg*NOFF + i];
    offs[i] = s;
}

// ---------------------------------------------------------------------------
// k_xt: transpose x[b][ci][pos] fp32 -> xTb[b][pos][ci] bf16 so the sampler's
// gathers are ci-coalesced. Runs AFTER k_reduce: xTb aliases dead pOff.
// LDS 64x65 tile (stride 65 -> conflict-free transpose reads).
// ---------------------------------------------------------------------------
__global__ __launch_bounds__(256) void k_xt(const float* __restrict__ x,
                                            short* __restrict__ xTb) {
    __shared__ float tile[64][65];
    int b = blockIdx.z;
    int p0 = blockIdx.x * 64;    // 49
    int c0 = blockIdx.y * 64;    // 4
    int t = threadIdx.x;
    int tp = t & 63;  int tc = t >> 6;
    #pragma unroll
    for (int i = 0; i < 16; ++i) {
        int ci = tc*16 + i;
        tile[ci][tp] = x[((size_t)b*CIN_ + c0 + ci)*HW_ + p0 + tp];
    }
    __syncthreads();
    #pragma unroll
    for (int i = 0; i < 16; ++i) {
        int p = tc*16 + i;
        xTb[((size_t)b*HW_ + p0 + p)*CIN_ + c0 + tp] = f2bf_bits(tile[tp][p]);
    }
}

// ---------------------------------------------------------------------------
// k_sample v3: build S[n][k] from TRANSPOSED bf16 x. Per (pos,kk): 4 clamped
// corner pos-indices + 4 validity-masked weights (reference semantics) in
// LDS; gather loop: lane covers 8 ci (16B short8 loads, fully coalesced —
// r7/r8's lane=pos scatter was 64 lines per wave-load). Half-wave handles
// one pos (32 lanes x 8 ci = 256 ci); wave does pos pairs.
// ---------------------------------------------------------------------------
__global__ __launch_bounds__(256) void k_sample(const short* __restrict__ xTb,
                                                const float* __restrict__ offs,
                                                short* __restrict__ S) {
    __shared__ int4   sI[64];
    __shared__ float4 sW[64];
    int t = threadIdx.x;
    int b = blockIdx.z, kk = blockIdx.y;
    int pos0 = blockIdx.x * 64;

    if (t < 64) {
        int pos = pos0 + t;
        int h = pos / WW_, w = pos % WW_;
        float dy = offs[(size_t)(b*18 + 2*kk    )*HW_ + pos];
        float dx = offs[(size_t)(b*18 + 2*kk + 1)*HW_ + pos];
        float py = (float)(h - 1 + kk/3) + dy;
        float px = (float)(w - 1 + kk%3) + dx;
        float y0f = floorf(py), x0f = floorf(px);
        int y0 = (int)y0f, x0 = (int)x0f;
        float ty = py - y0f, tx = px - x0f;
        bool vy0 = (y0   >= 0) && (y0   < HH_);
        bool vy1 = (y0+1 >= 0) && (y0+1 < HH_);
        bool vx0 = (x0   >= 0) && (x0   < WW_);
        bool vx1 = (x0+1 >= 0) && (x0+1 < WW_);
        int y0c = min(max(y0,   0), HH_-1), y1c = min(max(y0+1, 0), HH_-1);
        int x0c = min(max(x0,   0), WW_-1), x1c = min(max(x0+1, 0), WW_-1);
        sI[t] = make_int4(y0c*WW_+x0c, y0c*WW_+x1c, y1c*WW_+x0c, y1c*WW_+x1c);
        sW[t] = make_float4((vy0 && vx0) ? (1.f-ty)*(1.f-tx) : 0.f,
                            (vy0 && vx1) ? (1.f-ty)*tx       : 0.f,
                            (vy1 && vx0) ? ty*(1.f-tx)       : 0.f,
                            (vy1 && vx1) ? ty*tx             : 0.f);
    }
    __syncthreads();

    int lane = t & 63;  int g = t >> 6;
    int sub = lane >> 5;           // half-wave -> pos parity
    int cil = (lane & 31) * 8;     // 8 ci per lane
    const short* xb = xTb + (size_t)b*HW_*CIN_;

    #pragma unroll 1
    for (int pi = 0; pi < 8; ++pi) {
        int p = g*16 + pi*2 + sub;
        int4   id = sI[p];
        float4 wv = sW[p];
        short8 a = *(const short8*)(xb + (size_t)id.x*CIN_ + cil);
        short8 bq= *(const short8*)(xb + (size_t)id.y*CIN_ + cil);
        short8 c = *(const short8*)(xb + (size_t)id.z*CIN_ + cil);
        short8 d = *(const short8*)(xb + (size_t)id.w*CIN_ + cil);
        short8 pk;
        #pragma unroll
        for (int j = 0; j < 8; ++j) {
            float v = wv.x*bfbits2f(a[j]) + wv.y*bfbits2f(bq[j])
                    + wv.z*bfbits2f(c[j]) + wv.w*bfbits2f(d[j]);
            pk[j] = f2bf_bits(v);
        }
        *(short8*)(S + ((size_t)(b*HW_ + pos0 + p))*KDIM + kk*256 + cil) = pk;
    }
}

// ---------------------------------------------------------------------------
// k_gemm v2: BM=128, BN=64, BK=32, 256 thr = 4 waves (2x2), wave tile 64x32
// (8 MFMA : 6 LDS-b128 per iter vs r8's 4:6). Register double-buffer: next
// global tile loaded right after barrier, hidden under LDS reads + MFMA.
// Grid (2,196): m-pair adjacent -> S slice L2-shared; S HBM demand halved
// vs r8's 4 m-blocks (FETCH 114 MB, MfmaUtil 10%).
// ---------------------------------------------------------------------------
__global__ __launch_bounds__(256) void k_gemm(const short* __restrict__ At,
                                              const short* __restrict__ S,
                                              float* __restrict__ out) {
    __shared__ short sA[128][40];
    __shared__ short sB[64][40];
    int t = threadIdx.x;
    int m0 = blockIdx.x * 128;   // 2 m-blocks
    int n0 = blockIdx.y * 64;    // 196 n-blocks

    int arow = t >> 1, akof = (t & 1) * 16;   // sA staging: 2 short8/thread
    int brow = t >> 2, bkof = (t & 3) * 8;    // sB staging: 1 short8/thread

    int wv = t >> 6;
    int wm = (wv >> 1) * 64;     // 0 or 64
    int wn = (wv & 1) * 32;      // 0 or 32
    int lane = t & 63;
    int lm = lane & 15;
    int qd = lane >> 4;

    float4v acc[4][2];
    #pragma unroll
    for (int i = 0; i < 4; ++i)
        #pragma unroll
        for (int j = 0; j < 2; ++j) acc[i][j] = (float4v)(0.f);

    const short* gA = At + (size_t)(m0 + arow)*KDIM + akof;
    const short* gB = S  + (size_t)(n0 + brow)*KDIM + bkof;

    short8 pa0 = *(const short8*)(gA);
    short8 pa1 = *(const short8*)(gA + 8);
    short8 pb  = *(const short8*)(gB);

    for (int kt = 0; kt < KDIM; kt += 32) {
        __syncthreads();                       // prev-iter LDS reads done
        *(short8*)&sA[arow][akof]     = pa0;
        *(short8*)&sA[arow][akof + 8] = pa1;
        *(short8*)&sB[brow][bkof]     = pb;
        __syncthreads();
        if (kt + 32 < KDIM) {                  // prefetch next tile into regs
            pa0 = *(const short8*)(gA + kt + 32);
            pa1 = *(const short8*)(gA + kt + 40);
            pb  = *(const short8*)(gB + kt + 32);
        }
        short8 af[4], bf[2];
        #pragma unroll
        for (int i = 0; i < 4; ++i) af[i] = *(short8*)&sA[wm + i*16 + lm][qd*8];
        #pragma unroll
        for (int j = 0; j < 2; ++j) bf[j] = *(short8*)&sB[wn + j*16 + lm][qd*8];
        #pragma unroll
        for (int i = 0; i < 4; ++i)
            #pragma unroll
            for (int j = 0; j < 2; ++j)
                acc[i][j] = __builtin_amdgcn_mfma_f32_16x16x32_bf16(
                                af[i], bf[j], acc[i][j], 0, 0, 0);
    }

    // epilogue: C/D layout col=lane&15 (n), row=qd*4+r (m)
    int b    = blockIdx.y / 49;
    int posb = (blockIdx.y % 49) * 64;
    #pragma unroll
    for (int i = 0; i < 4; ++i)
        #pragma unroll
        for (int j = 0; j < 2; ++j) {
            int col = posb + wn + j*16 + lm;
            #pragma unroll
            for (int r = 0; r < 4; ++r) {
                int m = m0 + wm + i*16 + qd*4 + r;
                out[((size_t)b*COUT_ + m)*HW_ + col] = acc[i][j][r];
            }
        }
}

// ---------------------------------------------------------------------------
extern "C" void kernel_launch(void* const* d_in, const int* in_sizes, int n_in,
                              void* d_out, int out_size, void* d_ws, size_t ws_size,
                              hipStream_t stream) {
    const float* x   = (const float*)d_in[0];
    const float* wgt = (const float*)d_in[1];
    const float* ow  = (const float*)d_in[2];
    const float* ob  = (const float*)d_in[3];
    float* out = (float*)d_out;

    char* ws = (char*)d_ws;
    // ws layout (16B aligned): offs | At | owT2 | S | pOff
    // xTb (6.42 MB bf16) ALIASES pOff (7.23 MB): pOff dead after k_reduce,
    // k_xt runs after k_reduce. Total stays ~67.3 MB (known-good).
    float* offs = (float*)ws;                        // 225792*4   =   903168
    short* At   = (short*)(ws + 903168);             // 589824*2   =  1179648
    float* owT2 = (float*)(ws + 2082816);            // 55296*4    =   221184
    short* S    = (short*)(ws + 2304000);            // 28901376*2 = 57802752
    float* pOff = (float*)(ws + 60106752);           // 8*225792*4 =  7225344
    short* xTb  = (short*)(ws + 60106752);           // 3211264*2  =  6422528 (alias)

    k_owt    <<<dim3((CIN_*216 + 255)/256),   256, 0, stream>>>(ow, owT2);
    k_prep   <<<dim3((COUT_*KDIM + 255)/256), 256, 0, stream>>>(wgt, At);
    k_offset3<<<dim3(B_N*HH_, 8),             256, 0, stream>>>(x, owT2, pOff);
    k_reduce <<<dim3((NOFF + 255)/256),       256, 0, stream>>>(pOff, ob, offs);
    k_xt     <<<dim3(49, 4, 4),               256, 0, stream>>>(x, xTb);
    k_sample <<<dim3(49, 9, 4),               256, 0, stream>>>(xTb, offs, S);
    k_gemm   <<<dim3(2, 196),                 256, 0, stream>>>(At, S, out);
}

// Round 10
// 172.979 us; speedup vs baseline: 5.6304x; 1.0057x over previous
//
#include <hip/hip_runtime.h>
#include <hip/hip_bf16.h>

// Problem constants
#define B_N   4
#define CIN_  256
#define HH_   56
#define WW_   56
#define COUT_ 256
#define KK_   9
#define HW_   3136              // 56*56
#define KDIM  2304              // CIN_*KK_  (k index = kk*256 + ci)
#define NOFF  (B_N*18*HW_)      // 225792

typedef __attribute__((ext_vector_type(8))) short short8;   // 8 bf16 (4 VGPRs)
typedef __attribute__((ext_vector_type(4))) float float4v;  // MFMA accum

__device__ __forceinline__ short f2bf_bits(float v) {
    union { __hip_bfloat16 h; short s; } u;
    u.h = __float2bfloat16(v);
    return u.s;
}
__device__ __forceinline__ float bfbits2f(short s) {
    union { unsigned u; float f; } u2;
    u2.u = ((unsigned)(unsigned short)s) << 16;
    return u2.f;
}

// ---------------------------------------------------------------------------
// k_owt: offset weights [18][256][9] -> owT2[ci][c*12+kk] fp32 (stride 12 so
// each c-row is 16B-aligned for LDS float4 reads; kk=9..11 zero-filled).
// ---------------------------------------------------------------------------
__global__ __launch_bounds__(256) void k_owt(const float* __restrict__ ow,
                                             float* __restrict__ owT2) {
    int i = blockIdx.x*256 + threadIdx.x;        // i = ci*216 + c*12 + kk
    if (i >= CIN_*216) return;
    int ci = i / 216; int r = i % 216;
    int c = r / 12;   int kk = r % 12;
    owT2[i] = (kk < 9) ? ow[(size_t)(c*CIN_ + ci)*9 + kk] : 0.f;
}

// ---------------------------------------------------------------------------
// k_prep: weight [Cout][Cin][9] fp32 -> At[cout][k=kk*256+ci] bf16
// ---------------------------------------------------------------------------
__global__ __launch_bounds__(256) void k_prep(const float* __restrict__ wgt,
                                              short* __restrict__ At) {
    int i = blockIdx.x*256 + threadIdx.x;        // i = o*2304 + kk*256 + ci
    if (i >= COUT_*KDIM) return;
    int o = i / KDIM; int r = i % KDIM;
    int kk = r >> 8;  int ci = r & 255;
    At[i] = f2bf_bits(wgt[(size_t)(o*CIN_ + ci)*9 + kk]);
}

// ---------------------------------------------------------------------------
// k_offset3: 3x3 offset conv, ci-split 8 ways. DETERMINISTIC partials into
// pOff[cg] (no atomics — fp32 atomic jitter feeds floorf downstream and
// flips bilinear corners across replays). Weights staged in LDS, wave-uniform
// broadcast reads. red[] aliases weight LDS. ci loop MUST NOT unroll
// (r6: unroll -> 256 VGPR -> 1.9GB scratch spill).
// ---------------------------------------------------------------------------
__global__ __launch_bounds__(256) void k_offset3(const float* __restrict__ x,
                                                 const float* __restrict__ owT2,
                                                 float* __restrict__ pOff) {
    __shared__ float smem[32*216];               // 27.6 KB: weights, then red
    int t = threadIdx.x;
    int w = t & 63;  int q = t >> 6;
    int b = blockIdx.x / HH_, h = blockIdx.x % HH_;
    int cg = blockIdx.y;                         // 0..7
    const float* xb = x + (size_t)b*CIN_*HW_;

    {
        const float* src = owT2 + (size_t)cg*32*216;
        for (int i = t; i < 32*216; i += 256) smem[i] = src[i];
    }
    __syncthreads();

    float acc[18];
    #pragma unroll
    for (int c = 0; c < 18; ++c) acc[c] = 0.f;

    #pragma unroll 1
    for (int i = 0; i < 8; ++i) {
        int cil = q*8 + i;                       // ci local 0..31, wave-uniform
        const float* xp = xb + (size_t)(cg*32 + cil)*HW_;
        float v[3], patch[9];
        #pragma unroll
        for (int kh = 0; kh < 3; ++kh) {
            int yy = h - 1 + kh;
            v[kh] = (w < WW_ && yy >= 0 && yy < HH_) ? xp[yy*WW_ + w] : 0.f;
        }
        #pragma unroll
        for (int kh = 0; kh < 3; ++kh) {
            float c0 = v[kh];
            float l = __shfl_up(c0, 1);  if (w == 0) l = 0.f;
            float r = __shfl_down(c0, 1);        // lanes >=56 hold 0 -> col-56 pad ok
            patch[kh*3+0] = l; patch[kh*3+1] = c0; patch[kh*3+2] = r;
        }
        const float* wr_ = smem + cil*216;       // wave-uniform -> LDS broadcast
        #pragma unroll
        for (int c = 0; c < 18; ++c) {
            float4 wA = *(const float4*)(wr_ + c*12);
            float4 wB = *(const float4*)(wr_ + c*12 + 4);
            float  w8 = wr_[c*12 + 8];
            acc[c] += patch[0]*wA.x + patch[1]*wA.y + patch[2]*wA.z + patch[3]*wA.w
                    + patch[4]*wB.x + patch[5]*wB.y + patch[6]*wB.z + patch[7]*wB.w
                    + patch[8]*w8;
        }
    }
    __syncthreads();
    float* red = smem;                           // red[q][c][w] = q*1152+c*64+w
    #pragma unroll
    for (int c = 0; c < 18; ++c) red[q*1152 + c*64 + w] = acc[c];
    __syncthreads();
    float* pbase = pOff + (size_t)cg*NOFF;
    for (int o = t; o < 18*WW_; o += 256) {
        int c = o / WW_, w2 = o % WW_;
        float s = red[0*1152 + c*64 + w2] + red[1*1152 + c*64 + w2]
                + red[2*1152 + c*64 + w2] + red[3*1152 + c*64 + w2];
        pbase[(size_t)(b*18 + c)*HW_ + h*WW_ + w2] = s;
    }
}

// ---------------------------------------------------------------------------
// k_reduce: offs[i] = sum_{cg} pOff[cg][i] + bias (fixed order, bit-exact).
// ---------------------------------------------------------------------------
__global__ __launch_bounds__(256) void k_reduce(const float* __restrict__ pOff,
                                                const float* __restrict__ ob,
                                                float* __restrict__ offs) {
    int i = blockIdx.x*256 + threadIdx.x;
    if (i >= NOFF) return;
    float s = ob[(i / HW_) % 18];
    #pragma unroll
    for (int cg = 0; cg < 8; ++cg) s += pOff[(size_t)cg*NOFF + i];
    offs[i] = s;
}

// ---------------------------------------------------------------------------
// k_xt: transpose x[b][ci][pos] fp32 -> xTb[b][pos][ci] bf16 so the sampler's
// gathers are ci-coalesced. Runs AFTER k_reduce: xTb aliases dead pOff.
// ---------------------------------------------------------------------------
__global__ __launch_bounds__(256) void k_xt(const float* __restrict__ x,
                                            short* __restrict__ xTb) {
    __shared__ float tile[64][65];
    int b = blockIdx.z;
    int p0 = blockIdx.x * 64;    // 49
    int c0 = blockIdx.y * 64;    // 4
    int t = threadIdx.x;
    int tp = t & 63;  int tc = t >> 6;
    #pragma unroll
    for (int i = 0; i < 16; ++i) {
        int ci = tc*16 + i;
        tile[ci][tp] = x[((size_t)b*CIN_ + c0 + ci)*HW_ + p0 + tp];
    }
    __syncthreads();
    #pragma unroll
    for (int i = 0; i < 16; ++i) {
        int p = tc*16 + i;
        xTb[((size_t)b*HW_ + p0 + p)*CIN_ + c0 + tp] = f2bf_bits(tile[tp][p]);
    }
}

// ---------------------------------------------------------------------------
// k_sample v3: build S[n][k] from TRANSPOSED bf16 x. Per (pos,kk): 4 clamped
// corner pos-indices + 4 validity-masked weights (reference semantics) in
// LDS; gather loop: lane covers 8 ci (16B short8 loads, fully coalesced).
// unroll 2 -> 8 outstanding gathers per thread for latency hiding.
// ---------------------------------------------------------------------------
__global__ __launch_bounds__(256) void k_sample(const short* __restrict__ xTb,
                                                const float* __restrict__ offs,
                                                short* __restrict__ S) {
    __shared__ int4   sI[64];
    __shared__ float4 sW[64];
    int t = threadIdx.x;
    int b = blockIdx.z, kk = blockIdx.y;
    int pos0 = blockIdx.x * 64;

    if (t < 64) {
        int pos = pos0 + t;
        int h = pos / WW_, w = pos % WW_;
        float dy = offs[(size_t)(b*18 + 2*kk    )*HW_ + pos];
        float dx = offs[(size_t)(b*18 + 2*kk + 1)*HW_ + pos];
        float py = (float)(h - 1 + kk/3) + dy;
        float px = (float)(w - 1 + kk%3) + dx;
        float y0f = floorf(py), x0f = floorf(px);
        int y0 = (int)y0f, x0 = (int)x0f;
        float ty = py - y0f, tx = px - x0f;
        bool vy0 = (y0   >= 0) && (y0   < HH_);
        bool vy1 = (y0+1 >= 0) && (y0+1 < HH_);
        bool vx0 = (x0   >= 0) && (x0   < WW_);
        bool vx1 = (x0+1 >= 0) && (x0+1 < WW_);
        int y0c = min(max(y0,   0), HH_-1), y1c = min(max(y0+1, 0), HH_-1);
        int x0c = min(max(x0,   0), WW_-1), x1c = min(max(x0+1, 0), WW_-1);
        sI[t] = make_int4(y0c*WW_+x0c, y0c*WW_+x1c, y1c*WW_+x0c, y1c*WW_+x1c);
        sW[t] = make_float4((vy0 && vx0) ? (1.f-ty)*(1.f-tx) : 0.f,
                            (vy0 && vx1) ? (1.f-ty)*tx       : 0.f,
                            (vy1 && vx0) ? ty*(1.f-tx)       : 0.f,
                            (vy1 && vx1) ? ty*tx             : 0.f);
    }
    __syncthreads();

    int lane = t & 63;  int g = t >> 6;
    int sub = lane >> 5;           // half-wave -> pos parity
    int cil = (lane & 31) * 8;     // 8 ci per lane
    const short* xb = xTb + (size_t)b*HW_*CIN_;

    #pragma unroll 2
    for (int pi = 0; pi < 8; ++pi) {
        int p = g*16 + pi*2 + sub;
        int4   id = sI[p];
        float4 wv = sW[p];
        short8 a = *(const short8*)(xb + (size_t)id.x*CIN_ + cil);
        short8 bq= *(const short8*)(xb + (size_t)id.y*CIN_ + cil);
        short8 c = *(const short8*)(xb + (size_t)id.z*CIN_ + cil);
        short8 d = *(const short8*)(xb + (size_t)id.w*CIN_ + cil);
        short8 pk;
        #pragma unroll
        for (int j = 0; j < 8; ++j) {
            float v = wv.x*bfbits2f(a[j]) + wv.y*bfbits2f(bq[j])
                    + wv.z*bfbits2f(c[j]) + wv.w*bfbits2f(d[j]);
            pk[j] = f2bf_bits(v);
        }
        *(short8*)(S + ((size_t)(b*HW_ + pos0 + p))*KDIM + kk*256 + cil) = pk;
    }
}

// ---------------------------------------------------------------------------
// k_gemm v3: BM=128, BN=64, BK=64, 4 waves (2x2), wave tile 64x32.
// FRAGMENT-SWIZZLED LDS: 16B chunk (row,qd) lives at 16B-unit index
//   idx16 = ((row>>4)*8 + qd)*16 + ((row + 2*qd)&15)
// -> every wave read phase = 16 distinct units of one 256B block (2-way max,
// free per m136); writes 2-way. r9 counters: 5.4M conflict cycles with the
// [row][40] layout, MfmaUtil 12.5%, K-loop LDS-pipe-bound. BK=64 halves
// barrier count. Register prefetch of next tile hides global latency.
// ---------------------------------------------------------------------------
__global__ __launch_bounds__(256) void k_gemm(const short* __restrict__ At,
                                              const short* __restrict__ S,
                                              float* __restrict__ out) {
    __shared__ short sA[128*64];   // 16 KB, swizzled
    __shared__ short sB[64*64];    // 8 KB, swizzled
    int t = threadIdx.x;
    int m0 = blockIdx.x * 128;     // 2 m-blocks
    int n0 = blockIdx.y * 64;      // 196 n-blocks

    // staging assignments (global-coalesced in 128B row segments)
    int arow = t >> 1,  aqc = (t & 1) * 4;    // 4 chunks qd=aqc..aqc+3 (64B)
    int brow = t >> 2,  bqc = (t & 3) * 2;    // 2 chunks qd=bqc..bqc+1 (32B)

    int wv = t >> 6;
    int wm = (wv >> 1) * 64;       // 0 or 64
    int wn = (wv & 1) * 32;        // 0 or 32
    int lane = t & 63;
    int lm = lane & 15;
    int qd = lane >> 4;

    float4v acc[4][2];
    #pragma unroll
    for (int i = 0; i < 4; ++i)
        #pragma unroll
        for (int j = 0; j < 2; ++j) acc[i][j] = (float4v)(0.f);

    const short* gA = At + (size_t)(m0 + arow)*KDIM + aqc*8;
    const short* gB = S  + (size_t)(n0 + brow)*KDIM + bqc*8;

    // LDS write pointers (short* into swizzled arrays)
    short* wA[4]; short* wB[2];
    #pragma unroll
    for (int j = 0; j < 4; ++j) {
        int q = aqc + j;
        wA[j] = sA + (((arow >> 4)*8 + q)*16 + ((arow + 2*q) & 15))*8;
    }
    #pragma unroll
    for (int j = 0; j < 2; ++j) {
        int q = bqc + j;
        wB[j] = sB + (((brow >> 4)*8 + q)*16 + ((brow + 2*q) & 15))*8;
    }

    short8 pa[4], pb[2];
    #pragma unroll
    for (int j = 0; j < 4; ++j) pa[j] = *(const short8*)(gA + j*8);
    #pragma unroll
    for (int j = 0; j < 2; ++j) pb[j] = *(const short8*)(gB + j*8);

    for (int kt = 0; kt < KDIM; kt += 64) {
        __syncthreads();                       // prev-iter LDS reads done
        #pragma unroll
        for (int j = 0; j < 4; ++j) *(short8*)wA[j] = pa[j];
        #pragma unroll
        for (int j = 0; j < 2; ++j) *(short8*)wB[j] = pb[j];
        __syncthreads();
        if (kt + 64 < KDIM) {                  // prefetch next tile into regs
            #pragma unroll
            for (int j = 0; j < 4; ++j) pa[j] = *(const short8*)(gA + kt + 64 + j*8);
            #pragma unroll
            for (int j = 0; j < 2; ++j) pb[j] = *(const short8*)(gB + kt + 64 + j*8);
        }
        #pragma unroll
        for (int ks = 0; ks < 2; ++ks) {
            int qe = ks*4 + qd;
            int sw = (lm + 2*qe) & 15;
            short8 af[4], bf[2];
            #pragma unroll
            for (int i = 0; i < 4; ++i)
                af[i] = *(short8*)(sA + ((((wm>>4) + i)*8 + qe)*16 + sw)*8);
            #pragma unroll
            for (int j = 0; j < 2; ++j)
                bf[j] = *(short8*)(sB + ((((wn>>4) + j)*8 + qe)*16 + sw)*8);
            #pragma unroll
            for (int i = 0; i < 4; ++i)
                #pragma unroll
                for (int j = 0; j < 2; ++j)
                    acc[i][j] = __builtin_amdgcn_mfma_f32_16x16x32_bf16(
                                    af[i], bf[j], acc[i][j], 0, 0, 0);
        }
    }

    // epilogue: C/D layout col=lane&15 (n), row=qd*4+r (m)
    int b    = blockIdx.y / 49;
    int posb = (blockIdx.y % 49) * 64;
    #pragma unroll
    for (int i = 0; i < 4; ++i)
        #pragma unroll
        for (int j = 0; j < 2; ++j) {
            int col = posb + wn + j*16 + lm;
            #pragma unroll
            for (int r = 0; r < 4; ++r) {
                int m = m0 + wm + i*16 + qd*4 + r;
                out[((size_t)b*COUT_ + m)*HW_ + col] = acc[i][j][r];
            }
        }
}

// ---------------------------------------------------------------------------
extern "C" void kernel_launch(void* const* d_in, const int* in_sizes, int n_in,
                              void* d_out, int out_size, void* d_ws, size_t ws_size,
                              hipStream_t stream) {
    const float* x   = (const float*)d_in[0];
    const float* wgt = (const float*)d_in[1];
    const float* ow  = (const float*)d_in[2];
    const float* ob  = (const float*)d_in[3];
    float* out = (float*)d_out;

    char* ws = (char*)d_ws;
    // ws layout (16B aligned): offs | At | owT2 | S | pOff
    // xTb (6.42 MB bf16) ALIASES pOff (7.23 MB): pOff dead after k_reduce.
    float* offs = (float*)ws;                        // 225792*4   =   903168
    short* At   = (short*)(ws + 903168);             // 589824*2   =  1179648
    float* owT2 = (float*)(ws + 2082816);            // 55296*4    =   221184
    short* S    = (short*)(ws + 2304000);            // 28901376*2 = 57802752
    float* pOff = (float*)(ws + 60106752);           // 8*225792*4 =  7225344
    short* xTb  = (short*)(ws + 60106752);           // 3211264*2  =  6422528 (alias)

    k_owt    <<<dim3((CIN_*216 + 255)/256),   256, 0, stream>>>(ow, owT2);
    k_prep   <<<dim3((COUT_*KDIM + 255)/256), 256, 0, stream>>>(wgt, At);
    k_offset3<<<dim3(B_N*HH_, 8),             256, 0, stream>>>(x, owT2, pOff);
    k_reduce <<<dim3((NOFF + 255)/256),       256, 0, stream>>>(pOff, ob, offs);
    k_xt     <<<dim3(49, 4, 4),               256, 0, stream>>>(x, xTb);
    k_sample <<<dim3(49, 9, 4),               256, 0, stream>>>(xTb, offs, S);
    k_gemm   <<<dim3(2, 196),                 256, 0, stream>>>(At, S, out);
}

// Round 11
// 159.092 us; speedup vs baseline: 6.1219x; 1.0873x over previous
//
#include <hip/hip_runtime.h>
#include <hip/hip_bf16.h>

// Problem constants
#define B_N   4
#define CIN_  256
#define HH_   56
#define WW_   56
#define COUT_ 256
#define KK_   9
#define HW_   3136              // 56*56
#define KDIM  2304              // CIN_*KK_  (k index = kk*256 + ci)
#define NOFF  (B_N*18*HW_)      // 225792

typedef __attribute__((ext_vector_type(8))) short short8;   // 8 bf16 (4 VGPRs)
typedef __attribute__((ext_vector_type(4))) float float4v;  // MFMA accum

__device__ __forceinline__ short f2bf_bits(float v) {
    union { __hip_bfloat16 h; short s; } u;
    u.h = __float2bfloat16(v);
    return u.s;
}
__device__ __forceinline__ float bfbits2f(short s) {
    union { unsigned u; float f; } u2;
    u2.u = ((unsigned)(unsigned short)s) << 16;
    return u2.f;
}

// ---------------------------------------------------------------------------
// k_prep_all: 3 independent prep roles in ONE kernel (launch-gap reduction;
// r10 budget showed ~8us per inter-kernel gap across 7 launches).
//   bx [0,2304):      At[cout][k=kk*256+ci] bf16   (GEMM A matrix)
//   bx [2304,2520):   owT2[ci][c*12+kk] fp32       (offset-conv weights)
//   bx [2520,3304):   xTb[b][pos][ci] bf16         (transposed x for gathers)
// ---------------------------------------------------------------------------
#define NB_AT  2304
#define NB_OWT 216
#define NB_XT  784
__global__ __launch_bounds__(256) void k_prep_all(const float* __restrict__ x,
                                                  const float* __restrict__ wgt,
                                                  const float* __restrict__ ow,
                                                  short* __restrict__ At,
                                                  float* __restrict__ owT2,
                                                  short* __restrict__ xTb) {
    __shared__ float tile[64][65];
    int bx = blockIdx.x;
    int t = threadIdx.x;
    if (bx < NB_AT) {
        int i = bx*256 + t;                  // exactly COUT_*KDIM threads
        int o = i / KDIM; int r = i % KDIM;
        int kk = r >> 8;  int ci = r & 255;
        At[i] = f2bf_bits(wgt[(size_t)(o*CIN_ + ci)*9 + kk]);
    } else if (bx < NB_AT + NB_OWT) {
        int i = (bx - NB_AT)*256 + t;        // exactly CIN_*216 threads
        int ci = i / 216; int r = i % 216;
        int c = r / 12;   int kk = r % 12;
        owT2[i] = (kk < 9) ? ow[(size_t)(c*CIN_ + ci)*9 + kk] : 0.f;
    } else {
        int g = bx - NB_AT - NB_OWT;         // 0..783
        int b = g / 196; int r = g % 196;
        int c0 = (r / 49) * 64; int p0 = (r % 49) * 64;
        int tp = t & 63;  int tc = t >> 6;
        #pragma unroll
        for (int i = 0; i < 16; ++i) {
            int ci = tc*16 + i;
            tile[ci][tp] = x[((size_t)b*CIN_ + c0 + ci)*HW_ + p0 + tp];
        }
        __syncthreads();
        #pragma unroll
        for (int i = 0; i < 16; ++i) {
            int p = tc*16 + i;
            xTb[((size_t)b*HW_ + p0 + p)*CIN_ + c0 + tp] = f2bf_bits(tile[tp][p]);
        }
    }
}

// ---------------------------------------------------------------------------
// k_offset3: 3x3 offset conv, ci-split 8 ways. DETERMINISTIC partials into
// pOff[cg] (no atomics — fp32 atomic jitter feeds floorf downstream and
// flips bilinear corners across replays). Weights staged in LDS, wave-uniform
// broadcast reads. red[] aliases weight LDS. ci loop MUST NOT unroll
// (r6: unroll -> 256 VGPR -> 1.9GB scratch spill).
// ---------------------------------------------------------------------------
__global__ __launch_bounds__(256) void k_offset3(const float* __restrict__ x,
                                                 const float* __restrict__ owT2,
                                                 float* __restrict__ pOff) {
    __shared__ float smem[32*216];               // 27.6 KB: weights, then red
    int t = threadIdx.x;
    int w = t & 63;  int q = t >> 6;
    int b = blockIdx.x / HH_, h = blockIdx.x % HH_;
    int cg = blockIdx.y;                         // 0..7
    const float* xb = x + (size_t)b*CIN_*HW_;

    {
        const float* src = owT2 + (size_t)cg*32*216;
        for (int i = t; i < 32*216; i += 256) smem[i] = src[i];
    }
    __syncthreads();

    float acc[18];
    #pragma unroll
    for (int c = 0; c < 18; ++c) acc[c] = 0.f;

    #pragma unroll 1
    for (int i = 0; i < 8; ++i) {
        int cil = q*8 + i;                       // ci local 0..31, wave-uniform
        const float* xp = xb + (size_t)(cg*32 + cil)*HW_;
        float v[3], patch[9];
        #pragma unroll
        for (int kh = 0; kh < 3; ++kh) {
            int yy = h - 1 + kh;
            v[kh] = (w < WW_ && yy >= 0 && yy < HH_) ? xp[yy*WW_ + w] : 0.f;
        }
        #pragma unroll
        for (int kh = 0; kh < 3; ++kh) {
            float c0 = v[kh];
            float l = __shfl_up(c0, 1);  if (w == 0) l = 0.f;
            float r = __shfl_down(c0, 1);        // lanes >=56 hold 0 -> col-56 pad ok
            patch[kh*3+0] = l; patch[kh*3+1] = c0; patch[kh*3+2] = r;
        }
        const float* wr_ = smem + cil*216;       // wave-uniform -> LDS broadcast
        #pragma unroll
        for (int c = 0; c < 18; ++c) {
            float4 wA = *(const float4*)(wr_ + c*12);
            float4 wB = *(const float4*)(wr_ + c*12 + 4);
            float  w8 = wr_[c*12 + 8];
            acc[c] += patch[0]*wA.x + patch[1]*wA.y + patch[2]*wA.z + patch[3]*wA.w
                    + patch[4]*wB.x + patch[5]*wB.y + patch[6]*wB.z + patch[7]*wB.w
                    + patch[8]*w8;
        }
    }
    __syncthreads();
    float* red = smem;                           // red[q][c][w] = q*1152+c*64+w
    #pragma unroll
    for (int c = 0; c < 18; ++c) red[q*1152 + c*64 + w] = acc[c];
    __syncthreads();
    float* pbase = pOff + (size_t)cg*NOFF;
    for (int o = t; o < 18*WW_; o += 256) {
        int c = o / WW_, w2 = o % WW_;
        float s = red[0*1152 + c*64 + w2] + red[1*1152 + c*64 + w2]
                + red[2*1152 + c*64 + w2] + red[3*1152 + c*64 + w2];
        pbase[(size_t)(b*18 + c)*HW_ + h*WW_ + w2] = s;
    }
}

// ---------------------------------------------------------------------------
// k_reduce: offs[i] = sum_{cg} pOff[cg][i] + bias (fixed order, bit-exact).
// ---------------------------------------------------------------------------
__global__ __launch_bounds__(256) void k_reduce(const float* __restrict__ pOff,
                                                const float* __restrict__ ob,
                                                float* __restrict__ offs) {
    int i = blockIdx.x*256 + threadIdx.x;
    if (i >= NOFF) return;
    float s = ob[(i / HW_) % 18];
    #pragma unroll
    for (int cg = 0; cg < 8; ++cg) s += pOff[(size_t)cg*NOFF + i];
    offs[i] = s;
}

// ---------------------------------------------------------------------------
// k_gemm v4 (FUSED SAMPLING): implicit-im2col GEMM. B-tile is built by
// gathering 4 bilinear corners from L2-resident xTb and blending in regs —
// S matrix eliminated (58MB write + 58MB read + 1 launch). Params (corner
// idx + masked weights, identical math to old k_sample) computed once per
// block into LDS. BM=128, BN=64, BK=64, swizzled LDS (r10), register
// prefetch of A-tile + B-corner gathers. The gather/blend VMEM+VALU work
// fills the stalls of the formerly LDS/barrier-bound K-loop (r9: occupancy
// 1.5 blocks/CU -> nothing to overlap).
// ---------------------------------------------------------------------------
__global__ __launch_bounds__(256) void k_gemm(const short* __restrict__ At,
                                              const short* __restrict__ xTb,
                                              const float* __restrict__ offs,
                                              float* __restrict__ out) {
    __shared__ short sA[128*64];     // 16 KB, swizzled
    __shared__ short sB[64*64];      // 8 KB, swizzled
    __shared__ int4   sPI[9*64];     // 9 KB  corner indices
    __shared__ float4 sPW[9*64];     // 9 KB  corner weights
    int t = threadIdx.x;
    int m0   = blockIdx.x * 128;     // 2 m-blocks
    int b    = blockIdx.y / 49;
    int posb = (blockIdx.y % 49) * 64;

    // ---- bilinear params for this block's 64 positions x 9 kk ----
    for (int e = t; e < 9*64; e += 256) {
        int kk = e >> 6; int pl = e & 63;
        int pos = posb + pl;
        int h = pos / WW_, w = pos % WW_;
        float dy = offs[(size_t)(b*18 + 2*kk    )*HW_ + pos];
        float dx = offs[(size_t)(b*18 + 2*kk + 1)*HW_ + pos];
        float py = (float)(h - 1 + kk/3) + dy;
        float px = (float)(w - 1 + kk%3) + dx;
        float y0f = floorf(py), x0f = floorf(px);
        int y0 = (int)y0f, x0 = (int)x0f;
        float ty = py - y0f, tx = px - x0f;
        bool vy0 = (y0   >= 0) && (y0   < HH_);
        bool vy1 = (y0+1 >= 0) && (y0+1 < HH_);
        bool vx0 = (x0   >= 0) && (x0   < WW_);
        bool vx1 = (x0+1 >= 0) && (x0+1 < WW_);
        int y0c = min(max(y0,   0), HH_-1), y1c = min(max(y0+1, 0), HH_-1);
        int x0c = min(max(x0,   0), WW_-1), x1c = min(max(x0+1, 0), WW_-1);
        sPI[e] = make_int4(y0c*WW_+x0c, y0c*WW_+x1c, y1c*WW_+x0c, y1c*WW_+x1c);
        sPW[e] = make_float4((vy0 && vx0) ? (1.f-ty)*(1.f-tx) : 0.f,
                             (vy0 && vx1) ? (1.f-ty)*tx       : 0.f,
                             (vy1 && vx0) ? ty*(1.f-tx)       : 0.f,
                             (vy1 && vx1) ? ty*tx             : 0.f);
    }
    __syncthreads();                 // sPI/sPW read-only from here on

    int arow = t >> 1,  aqc = (t & 1) * 4;    // A staging: 4 chunks (64B)
    int brow = t >> 2,  bqc = (t & 3) * 2;    // B staging: 2 chunks (32B)

    int wv = t >> 6;
    int wm = (wv >> 1) * 64;
    int wn = (wv & 1) * 32;
    int lane = t & 63;
    int lm = lane & 15;
    int qd = lane >> 4;

    float4v acc[4][2];
    #pragma unroll
    for (int i = 0; i < 4; ++i)
        #pragma unroll
        for (int j = 0; j < 2; ++j) acc[i][j] = (float4v)(0.f);

    const short* gA = At + (size_t)(m0 + arow)*KDIM + aqc*8;
    const short* xb = xTb + (size_t)b*HW_*CIN_;

    short* wA[4]; short* wB[2];
    #pragma unroll
    for (int j = 0; j < 4; ++j) {
        int q = aqc + j;
        wA[j] = sA + (((arow >> 4)*8 + q)*16 + ((arow + 2*q) & 15))*8;
    }
    #pragma unroll
    for (int j = 0; j < 2; ++j) {
        int q = bqc + j;
        wB[j] = sB + (((brow >> 4)*8 + q)*16 + ((brow + 2*q) & 15))*8;
    }

    short8 pa[4], cg[2][4];
    float4 bwv;
    // prologue: gather tiles for kt=0 (kk=0)
    #pragma unroll
    for (int j = 0; j < 4; ++j) pa[j] = *(const short8*)(gA + j*8);
    {
        int4 id = sPI[brow]; bwv = sPW[brow];
        #pragma unroll
        for (int j = 0; j < 2; ++j) {
            int ci0 = (bqc + j)*8;
            cg[j][0] = *(const short8*)(xb + (size_t)id.x*CIN_ + ci0);
            cg[j][1] = *(const short8*)(xb + (size_t)id.y*CIN_ + ci0);
            cg[j][2] = *(const short8*)(xb + (size_t)id.z*CIN_ + ci0);
            cg[j][3] = *(const short8*)(xb + (size_t)id.w*CIN_ + ci0);
        }
    }

    for (int kt = 0; kt < KDIM; kt += 64) {
        // blend the gathered corners (bf16 product identical to old k_sample)
        short8 pk[2];
        #pragma unroll
        for (int j = 0; j < 2; ++j)
            #pragma unroll
            for (int e = 0; e < 8; ++e)
                pk[j][e] = f2bf_bits(bwv.x*bfbits2f(cg[j][0][e])
                                   + bwv.y*bfbits2f(cg[j][1][e])
                                   + bwv.z*bfbits2f(cg[j][2][e])
                                   + bwv.w*bfbits2f(cg[j][3][e]));
        __syncthreads();                       // prev-iter LDS reads done
        #pragma unroll
        for (int j = 0; j < 4; ++j) *(short8*)wA[j] = pa[j];
        #pragma unroll
        for (int j = 0; j < 2; ++j) *(short8*)wB[j] = pk[j];
        __syncthreads();
        int kt2 = kt + 64;
        if (kt2 < KDIM) {                      // prefetch next tiles
            #pragma unroll
            for (int j = 0; j < 4; ++j) pa[j] = *(const short8*)(gA + kt2 + j*8);
            int kk2 = kt2 >> 8;
            int4 id = sPI[kk2*64 + brow]; bwv = sPW[kk2*64 + brow];
            int cb = kt2 & 255;
            #pragma unroll
            for (int j = 0; j < 2; ++j) {
                int ci0 = cb + (bqc + j)*8;
                cg[j][0] = *(const short8*)(xb + (size_t)id.x*CIN_ + ci0);
                cg[j][1] = *(const short8*)(xb + (size_t)id.y*CIN_ + ci0);
                cg[j][2] = *(const short8*)(xb + (size_t)id.z*CIN_ + ci0);
                cg[j][3] = *(const short8*)(xb + (size_t)id.w*CIN_ + ci0);
            }
        }
        #pragma unroll
        for (int ks = 0; ks < 2; ++ks) {
            int qe = ks*4 + qd;
            int sw = (lm + 2*qe) & 15;
            short8 af[4], bf[2];
            #pragma unroll
            for (int i = 0; i < 4; ++i)
                af[i] = *(short8*)(sA + ((((wm>>4) + i)*8 + qe)*16 + sw)*8);
            #pragma unroll
            for (int j = 0; j < 2; ++j)
                bf[j] = *(short8*)(sB + ((((wn>>4) + j)*8 + qe)*16 + sw)*8);
            #pragma unroll
            for (int i = 0; i < 4; ++i)
                #pragma unroll
                for (int j = 0; j < 2; ++j)
                    acc[i][j] = __builtin_amdgcn_mfma_f32_16x16x32_bf16(
                                    af[i], bf[j], acc[i][j], 0, 0, 0);
        }
    }

    // epilogue: C/D layout col=lane&15 (n), row=qd*4+r (m)
    #pragma unroll
    for (int i = 0; i < 4; ++i)
        #pragma unroll
        for (int j = 0; j < 2; ++j) {
            int col = posb + wn + j*16 + lm;
            #pragma unroll
            for (int r = 0; r < 4; ++r) {
                int m = m0 + wm + i*16 + qd*4 + r;
                out[((size_t)b*COUT_ + m)*HW_ + col] = acc[i][j][r];
            }
        }
}

// ---------------------------------------------------------------------------
extern "C" void kernel_launch(void* const* d_in, const int* in_sizes, int n_in,
                              void* d_out, int out_size, void* d_ws, size_t ws_size,
                              hipStream_t stream) {
    const float* x   = (const float*)d_in[0];
    const float* wgt = (const float*)d_in[1];
    const float* ow  = (const float*)d_in[2];
    const float* ob  = (const float*)d_in[3];
    float* out = (float*)d_out;

    char* ws = (char*)d_ws;
    // ws layout (16B aligned): offs | At | owT2 | xTb | pOff  (~16 MB; S gone)
    // NOTE: xTb no longer aliases pOff — xTb is written (prep_all) BEFORE
    // pOff (offset3); aliasing would corrupt.
    float* offs = (float*)ws;                        // 225792*4  =   903168
    short* At   = (short*)(ws + 903168);             // 589824*2  =  1179648
    float* owT2 = (float*)(ws + 2082816);            // 55296*4   =   221184
    short* xTb  = (short*)(ws + 2304000);            // 3211264*2 =  6422528
    float* pOff = (float*)(ws + 8726528);            // 8*225792*4=  7225344

    k_prep_all<<<dim3(NB_AT + NB_OWT + NB_XT), 256, 0, stream>>>(x, wgt, ow, At, owT2, xTb);
    k_offset3 <<<dim3(B_N*HH_, 8),             256, 0, stream>>>(x, owT2, pOff);
    k_reduce  <<<dim3((NOFF + 255)/256),       256, 0, stream>>>(pOff, ob, offs);
    k_gemm    <<<dim3(2, 196),                 256, 0, stream>>>(At, xTb, offs, out);
}